// Round 12
// baseline (2142.291 us; speedup 1.0000x reference)
//
#include <hip/hip_runtime.h>
#include <stdint.h>
#include <math.h>

// DialogueSNN: B=8, S=256, V=32000, E=64, H=128, T=20 inner steps.
// All internal math in f64 to track the high-precision numpy reference.
//
// R11: TLP fix (512-thr blocks, 4 waves/SIMD) -> 363 cy/step, VALUBusy 43%.
// R12: the gather sum is NOT part of the serial mm-recursion -> software-
// pipeline it: masks 2-deep, slot VALUES 1-deep in registers. Per step we
// issue (a) mask for step+2, (b) predicated first-spike value reads for
// step+1 (both halves), and compute step s from values issued one full
// iteration earlier (~230cy slack > 120cy LDS latency). Residual >=2-spike
// cases (P~6%/half) stay in rare wave-uniform while loops. Pipeline flushes
// at chunk boundaries (clamped idx). k1: cur1[t+1] prefetched (20-step slack).
//
// Workspace: cur1 (256*8*128 f64 = 2 MB) + masks (5120*16 u64 = 640 KB).

#define BB 8
#define SS 256
#define EE 64
#define HH 128
#define VV 32000
#define TT 20
#define NG (SS*TT)   // 5120 total steps

#define TBV 128      // v-columns per block in k2 (w2s slice = 64 KB)
#define NTH 512      // k2 threads: 128 v-cols x 4 batches
#define CHS 128      // steps per mask chunk (NG % CHS == 0 -> 40 chunks)
#define NCH (NG/CHS)
#define TOPB 0x8000000000000000ull

typedef unsigned long long u64;
typedef const __attribute__((address_space(1))) void gvoid;
typedef __attribute__((address_space(3))) void lvoid;

__global__ __launch_bounds__(HH) void k0_cur1(
    const int* __restrict__ x, const float* __restrict__ embed,
    const float* __restrict__ W1, const float* __restrict__ b1,
    double* __restrict__ cur1)
{
    int blk = blockIdx.x;          // t*BB + b
    int t = blk >> 3, b = blk & 7;
    int h = threadIdx.x;           // 0..127
    int ix = x[b*SS + t];
    const float* erow = embed + (size_t)ix * EE;
    double acc = 0.0;
    #pragma unroll
    for (int e = 0; e < EE; ++e)
        acc += (double)erow[e] * (double)W1[e*HH + h];
    acc += (double)b1[h];
    cur1[((size_t)t*BB + b)*HH + h] = acc;
}

__global__ __launch_bounds__(64) void k1_l1(
    const double* __restrict__ cur1, u64* __restrict__ masks,
    float* __restrict__ out_mem1)
{
    // one wave per block; blockIdx.x = b*2 + half; lane = h within half
    int b = blockIdx.x >> 1, half = blockIdx.x & 1;
    int lane = threadIdx.x;
    int h = half*64 + lane;
    double m = 0.0;
    double r = 0.0;   // reset at step s == spk at step s-1; heaviside(0-1)=0 init
    double cur = cur1[(size_t)b*HH + h];            // t = 0
    for (int t = 0; t < SS; ++t) {
        // prefetch next t's cur early: 20 steps of slack hide the load
        int tn = (t + 1 < SS) ? t + 1 : t;
        double nxt = cur1[((size_t)tn*BB + b)*HH + h];
        #pragma unroll
        for (int s = 0; s < TT; ++s) {
            m = __builtin_fma(0.95, m, cur) - r;   // chain: fma -> sub
            bool spk = m > 1.0;
            r = spk ? 1.0 : 0.0;
            u64 msk = __ballot(spk);
            if (lane == 0) masks[(size_t)(t*TT + s)*(2*BB) + b*2 + half] = msk;
        }
        cur = nxt;
    }
    out_mem1[b*HH + h] = (float)m;
}

__global__ __launch_bounds__(NTH, 4) void k2_l2(
    const float* __restrict__ W2, const float* __restrict__ b2,
    const u64* __restrict__ masks, float* __restrict__ out)
{
    __shared__ float w2s[HH][TBV];            // 64 KB, resident whole kernel
    __shared__ ulonglong2 mbuf[2][CHS*4];     // 2 x 8 KB mask chunk buffers
    const int tid = threadIdx.x;
    const int vl  = tid & 127;                // v within tile
    const int bq  = tid >> 7;                 // 0..3 batch within group
    const int v0 = blockIdx.x * TBV;
    const int by = blockIdx.y;                // batch group (4 batches each)
    const int b  = by*4 + bq;
    for (int i = tid; i < HH*TBV; i += NTH) {
        int hh = i >> 7;
        w2s[hh][i & 127] = W2[(size_t)hh*VV + v0 + (i & 127)];
    }

    // --- mask chunk staging via global_load_lds (unsinkable DMA) ---
    // one call: 512 lanes x 16B = 8 KB = 128 steps. LDS byte tid*16 =
    // step(tid>>2)*64 + chain(tid&3)*16 -> linear [step][chain] layout.
    const char* mbase = (const char*)masks + (size_t)by*64
                        + (size_t)(tid >> 2)*128 + (size_t)(tid & 3)*16;
    const int wv = tid >> 6;                  // wave id (uniform per wave)
    #define STAGE(c, bsel)                                                       \
        __builtin_amdgcn_global_load_lds(                                        \
            (gvoid*)(mbase + (size_t)(c)*(CHS*128)),                             \
            (lvoid*)((char*)&mbuf[(bsel)][0] + wv*1024), 16, 0, 0);

    STAGE(0, 0);
    __syncthreads();                          // w2s + chunk 0 ready

    const int v = v0 + vl;
    const double b2v = (double)b2[v];
    double mm = 0.0, rr = 0.0;
    float* outp = out + (size_t)b*SS*VV + v;

    int ic = 0;                               // inner-step counter (emit at TT)
    int buf = 0;
    for (int c = 0; c < NCH; ++c) {
        if (c + 1 < NCH) STAGE(c + 1, buf ^ 1);
        const ulonglong2* mc = &mbuf[buf][0];

        // pipeline prologue: A = mask[0], Bv = mask[1], wA = slot values[0]
        ulonglong2 A  = mc[bq];
        ulonglong2 Bv = mc[4 + bq];
        int hA0 = __builtin_ctzll(A.x | TOPB);
        int hA1 = __builtin_ctzll(A.y | TOPB);
        float wA0 = w2s[hA0][vl];
        float wA1 = w2s[64 + hA1][vl];

        for (int sic = 0; sic < CHS; ++sic) {
            // issue mask for step sic+2 (clamped within chunk)
            int s2 = sic + 2; if (s2 > CHS - 1) s2 = CHS - 1;
            ulonglong2 C = mc[s2*4 + bq];
            // issue slot-value reads for step sic+1 (predicated-safe index)
            int hB0 = __builtin_ctzll(Bv.x | TOPB);
            int hB1 = __builtin_ctzll(Bv.y | TOPB);
            float wB0 = w2s[hB0][vl];
            float wB1 = w2s[64 + hB1][vl];

            const bool emit = (++ic == TT);
            if (emit) ic = 0;

            // compute step sic from A + values issued last iteration
            double sum = (A.x ? (double)wA0 : 0.0);
            u64 r0 = A.x & (A.x - 1);
            while (r0) { int hh = __builtin_ctzll(r0); r0 &= (r0 - 1);
                         sum += (double)w2s[hh][vl]; }
            sum += (A.y ? (double)wA1 : 0.0);
            u64 r1 = A.y & (A.y - 1);
            while (r1) { int hh = __builtin_ctzll(r1); r1 &= (r1 - 1);
                         sum += (double)w2s[64 + hh][vl]; }
            double cur = sum + b2v;                    // matches np op order
            mm = __builtin_fma(0.95, mm, cur) - rr;
            bool spk = mm > 1.0;
            rr = spk ? 1.0 : 0.0;
            if (emit) { *outp = spk ? 1.0f : 0.0f; outp += VV; }

            // rotate pipeline
            A = Bv; Bv = C; wA0 = wB0; wA1 = wB1;
        }
        __syncthreads();                      // chunk c done; c+1's DMA landed
        buf ^= 1;
    }

    float* mem2out = out + (size_t)BB*SS*VV + (size_t)BB*HH;
    mem2out[(size_t)b*VV + v] = (float)mm;
}

extern "C" void kernel_launch(void* const* d_in, const int* in_sizes, int n_in,
                              void* d_out, int out_size, void* d_ws, size_t ws_size,
                              hipStream_t stream)
{
    const int*   x     = (const int*)  d_in[0];
    const float* embed = (const float*)d_in[1];
    const float* W1    = (const float*)d_in[2];
    const float* b1    = (const float*)d_in[3];
    const float* W2    = (const float*)d_in[4];
    const float* b2    = (const float*)d_in[5];
    float* out = (float*)d_out;

    // workspace carve: cur1 f64 [256*8*128] then masks u64 [5120*16]
    double* cur1 = (double*)d_ws;
    u64* masks = (u64*)((char*)d_ws + (size_t)SS*BB*HH*sizeof(double));

    k0_cur1<<<SS*BB, HH, 0, stream>>>(x, embed, W1, b1, cur1);
    k1_l1<<<BB*2, 64, 0, stream>>>(cur1, masks, out + (size_t)BB*SS*VV);
    k2_l2<<<dim3(VV/TBV, BB/4), NTH, 0, stream>>>(W2, b2, masks, out);
}

// Round 15
// 1132.598 us; speedup vs baseline: 1.8915x; 1.8915x over previous
//
#include <hip/hip_runtime.h>
#include <stdint.h>
#include <math.h>

// DialogueSNN: B=8, S=256, V=32000, E=64, H=128, T=20 inner steps.
// All internal math in f64 to track the high-precision numpy reference.
//
// R11: TLP fix -> k2 775us (363 cy/step, VALUBusy 43%). R12 value-pipeline
// regressed (issue 2x) -> reverted. R13 writelane builtin doesn't exist.
// R14 k1: collect the 20 wave-uniform ballots of each t in 20 statically-
//   indexed u64 locals (SGPR-resident), then ONE if(lane==0) burst of 20
//   imm-offset stores per t (one exec toggle per t, not per step).
//   Keeps R12's cur1 prefetch.
// R14 k2 (= R13's untested restructure):
//   - wave-uniform skip when mask==0
//   - first spike of EACH half extracted upfront -> 2 co-issued ds_reads;
//     m1's wait hides under m0's residual loop
//   - residual loops pairwise: 2 independent reads per iteration, 1 wait
//   - np add order preserved (half-0 bits ascending, then half-1)
//
// Workspace: cur1 (256*8*128 f64 = 2 MB) + masks (5120*16 u64 = 640 KB).

#define BB 8
#define SS 256
#define EE 64
#define HH 128
#define VV 32000
#define TT 20
#define NG (SS*TT)   // 5120 total steps

#define TBV 128      // v-columns per block in k2 (w2s slice = 64 KB)
#define NTH 512      // k2 threads: 128 v-cols x 4 batches
#define CHS 128      // steps per mask chunk (NG % CHS == 0 -> 40 chunks)
#define NCH (NG/CHS)
#define TOPB 0x8000000000000000ull

typedef unsigned long long u64;
typedef const __attribute__((address_space(1))) void gvoid;
typedef __attribute__((address_space(3))) void lvoid;

__global__ __launch_bounds__(HH) void k0_cur1(
    const int* __restrict__ x, const float* __restrict__ embed,
    const float* __restrict__ W1, const float* __restrict__ b1,
    double* __restrict__ cur1)
{
    int blk = blockIdx.x;          // t*BB + b
    int t = blk >> 3, b = blk & 7;
    int h = threadIdx.x;           // 0..127
    int ix = x[b*SS + t];
    const float* erow = embed + (size_t)ix * EE;
    double acc = 0.0;
    #pragma unroll
    for (int e = 0; e < EE; ++e)
        acc += (double)erow[e] * (double)W1[e*HH + h];
    acc += (double)b1[h];
    cur1[((size_t)t*BB + b)*HH + h] = acc;
}

__global__ __launch_bounds__(64) void k1_l1(
    const double* __restrict__ cur1, u64* __restrict__ masks,
    float* __restrict__ out_mem1)
{
    // one wave per block; blockIdx.x = b*2 + half; lane = h within half
    int b = blockIdx.x >> 1, half = blockIdx.x & 1;
    int lane = threadIdx.x;
    int h = half*64 + lane;
    double m = 0.0;
    double r = 0.0;   // reset at step s == spk at step s-1; heaviside(0-1)=0 init
    double cur = cur1[(size_t)b*HH + h];            // t = 0
    u64* mrow = masks + b*2 + half;                 // + (t*TT+s)*2*BB
    for (int t = 0; t < SS; ++t) {
        // prefetch next t's cur early: 20 steps of slack hide the load
        int tn = (t + 1 < SS) ? t + 1 : t;
        double nxt = cur1[((size_t)tn*BB + b)*HH + h];
        u64 ms[TT];                                 // statically indexed -> regs
        #pragma unroll
        for (int s = 0; s < TT; ++s) {
            m = __builtin_fma(0.95, m, cur) - r;   // chain: fma -> sub
            bool spk = m > 1.0;
            r = spk ? 1.0 : 0.0;
            ms[s] = __ballot(spk);                 // wave-uniform
        }
        if (lane == 0) {                           // ONE exec toggle per t
            u64* p = mrow + (size_t)t*TT*(2*BB);
            #pragma unroll
            for (int s = 0; s < TT; ++s)
                p[(size_t)s*(2*BB)] = ms[s];       // imm-offset stores
        }
        cur = nxt;
    }
    out_mem1[b*HH + h] = (float)m;
}

__global__ __launch_bounds__(NTH, 4) void k2_l2(
    const float* __restrict__ W2, const float* __restrict__ b2,
    const u64* __restrict__ masks, float* __restrict__ out)
{
    __shared__ float w2s[HH][TBV];            // 64 KB, resident whole kernel
    __shared__ ulonglong2 mbuf[2][CHS*4];     // 2 x 8 KB mask chunk buffers
    const int tid = threadIdx.x;
    const int vl  = tid & 127;                // v within tile
    const int bq  = tid >> 7;                 // 0..3 batch within group
    const int v0 = blockIdx.x * TBV;
    const int by = blockIdx.y;                // batch group (4 batches each)
    const int b  = by*4 + bq;
    for (int i = tid; i < HH*TBV; i += NTH) {
        int hh = i >> 7;
        w2s[hh][i & 127] = W2[(size_t)hh*VV + v0 + (i & 127)];
    }

    // --- mask chunk staging via global_load_lds (unsinkable DMA) ---
    // one call: 512 lanes x 16B = 8 KB = 128 steps. LDS byte tid*16 =
    // step(tid>>2)*64 + chain(tid&3)*16 -> linear [step][chain] layout.
    const char* mbase = (const char*)masks + (size_t)by*64
                        + (size_t)(tid >> 2)*128 + (size_t)(tid & 3)*16;
    const int wv = tid >> 6;                  // wave id (uniform per wave)
    #define STAGE(c, bsel)                                                       \
        __builtin_amdgcn_global_load_lds(                                        \
            (gvoid*)(mbase + (size_t)(c)*(CHS*128)),                             \
            (lvoid*)((char*)&mbuf[(bsel)][0] + wv*1024), 16, 0, 0);

    STAGE(0, 0);
    __syncthreads();                          // w2s + chunk 0 ready

    const int v = v0 + vl;
    const double b2v = (double)b2[v];
    double mm = 0.0, rr = 0.0;
    float* outp = out + (size_t)b*SS*VV + v;

    int ic = 0;                               // inner-step counter (emit at TT)
    int buf = 0;
    for (int c = 0; c < NCH; ++c) {
        if (c + 1 < NCH) STAGE(c + 1, buf ^ 1);
        const ulonglong2* mc = &mbuf[buf][0];

        ulonglong2 cm = mc[bq];               // 1-deep reg prefetch
        for (int sic = 0; sic < CHS; ++sic) {
            const int nsic = (sic + 1 < CHS) ? sic + 1 : sic;
            ulonglong2 nm = mc[nsic*4 + bq];  // broadcast ds_read_b128

            const bool emit = (++ic == TT);
            if (emit) ic = 0;

            u64 m0 = cm.x, m1 = cm.y;
            double sum = 0.0;
            if (m0 | m1) {                    // wave-uniform skip
                // first spike of each half: both reads co-issued here
                int h0 = __builtin_ctzll(m0 | TOPB);
                int h1 = __builtin_ctzll(m1 | TOPB);
                float a0 = w2s[h0][vl];
                float a1 = w2s[64 + h1][vl];
                u64 n0 = m0 & (m0 - 1), n1 = m1 & (m1 - 1);

                sum += m0 ? (double)a0 : 0.0;
                while (n0) {                  // pairwise residual, half 0
                    int i0 = __builtin_ctzll(n0); n0 &= n0 - 1;
                    int i1 = __builtin_ctzll(n0 | TOPB);
                    bool two = n0 != 0;
                    n0 &= n0 - 1;
                    float p = w2s[i0][vl];
                    float q = w2s[i1][vl];
                    sum += (double)p;
                    sum += two ? (double)q : 0.0;
                }
                sum += m1 ? (double)a1 : 0.0;
                while (n1) {                  // pairwise residual, half 1
                    int i0 = __builtin_ctzll(n1); n1 &= n1 - 1;
                    int i1 = __builtin_ctzll(n1 | TOPB);
                    bool two = n1 != 0;
                    n1 &= n1 - 1;
                    float p = w2s[64 + i0][vl];
                    float q = w2s[64 + i1][vl];
                    sum += (double)p;
                    sum += two ? (double)q : 0.0;
                }
            }
            double cur = sum + b2v;                    // matches np op order
            mm = __builtin_fma(0.95, mm, cur) - rr;
            bool spk = mm > 1.0;
            rr = spk ? 1.0 : 0.0;
            if (emit) { *outp = spk ? 1.0f : 0.0f; outp += VV; }
            cm = nm;
        }
        __syncthreads();                      // chunk c done; c+1's DMA landed
        buf ^= 1;
    }

    float* mem2out = out + (size_t)BB*SS*VV + (size_t)BB*HH;
    mem2out[(size_t)b*VV + v] = (float)mm;
}

extern "C" void kernel_launch(void* const* d_in, const int* in_sizes, int n_in,
                              void* d_out, int out_size, void* d_ws, size_t ws_size,
                              hipStream_t stream)
{
    const int*   x     = (const int*)  d_in[0];
    const float* embed = (const float*)d_in[1];
    const float* W1    = (const float*)d_in[2];
    const float* b1    = (const float*)d_in[3];
    const float* W2    = (const float*)d_in[4];
    const float* b2    = (const float*)d_in[5];
    float* out = (float*)d_out;

    // workspace carve: cur1 f64 [256*8*128] then masks u64 [5120*16]
    double* cur1 = (double*)d_ws;
    u64* masks = (u64*)((char*)d_ws + (size_t)SS*BB*HH*sizeof(double));

    k0_cur1<<<SS*BB, HH, 0, stream>>>(x, embed, W1, b1, cur1);
    k1_l1<<<BB*2, 64, 0, stream>>>(cur1, masks, out + (size_t)BB*SS*VV);
    k2_l2<<<dim3(VV/TBV, BB/4), NTH, 0, stream>>>(W2, b2, masks, out);
}